// Round 15
// baseline (483.803 us; speedup 1.0000x reference)
//
#include <hip/hip_runtime.h>
#include <hip/hip_bf16.h>

typedef __attribute__((ext_vector_type(8))) short bf16x8;
typedef __attribute__((ext_vector_type(4))) float f32x4;
typedef __attribute__((ext_vector_type(4))) short s16x4;

#define HID 512
#define NB 32
#define SEQL 4096
#define BM 32
#define NBLK 4096       // 131072 rows / 32

// workspace layout (bytes)
#define WS_BP    0              // packed bf16 W_enc: 512 KB
#define WS_DPROJ (512*1024)     // fp32 32x512: 64 KB
#define WS_SUM   (576*1024)     // fp32 32: 128 B

__device__ __forceinline__ short f2bf(float f) {
    unsigned u = __float_as_uint(f);
    unsigned r = (u + 0x7fffu + ((u >> 16) & 1u)) >> 16;   // RNE
    return (short)r;
}

__device__ __forceinline__ float fast_tanh(float x) {
    float e = __expf(2.0f * x);
    float r = __builtin_amdgcn_rcpf(e + 1.0f);
    return 1.0f - 2.0f * r;
}

// HW packed f32->bf16 RNE (no builtin on gfx950 — inline asm)
__device__ __forceinline__ unsigned cvtpk(float lo, float hi) {
    unsigned r;
    asm("v_cvt_pk_bf16_f32 %0, %1, %2" : "=v"(r) : "v"(lo), "v"(hi));
    return r;
}

// ---------------------------------------------------------------------------
// K_pre (unchanged, measured-good): (a) W_enc pack fp32->bf16 B-frag layout
// [blk 0..127], (b) dproj GEMV 8-way h-parallel [blk 128..639],
// (c) zero ctx + sumacc [blk 640..703]
// ---------------------------------------------------------------------------
__global__ void k_pre(const float* __restrict__ We, short* __restrict__ Bp,
                      const float* __restrict__ dec, const float* __restrict__ Wd,
                      const float* __restrict__ be, const float* __restrict__ bd,
                      float* __restrict__ dproj, float* __restrict__ out,
                      float* __restrict__ sumacc) {
    const int blk = blockIdx.x, t = threadIdx.x;
    if (blk < 128) {
        // Bp[kc32][nt][lane][j] = We[kc32*32 + (lane>>4)*8 + j][nt*16 + (lane&15)]
        int tid  = blk * 256 + t;
        int lane = tid & 63;
        int nt   = (tid >> 6) & 31;
        int kc   = tid >> 11;
        int k0   = kc * 32 + (lane >> 4) * 8;
        int n    = nt * 16 + (lane & 15);
        bf16x8 v;
#pragma unroll
        for (int j = 0; j < 8; ++j) v[j] = f2bf(We[(size_t)(k0 + j) * HID + n]);
        *(bf16x8*)&Bp[(size_t)tid * 8] = v;
    } else if (blk < 640) {
        __shared__ float red[8][33];
        int bid2 = blk - 128;
        int b  = bid2 >> 4, kg = bid2 & 15;     // 32 batches x 16 k-groups
        int kl = t & 31,    hc = t >> 5;        // 32 k-cols x 8 h-chunks
        int k  = kg * 32 + kl;
        const float* dr = dec + (size_t)b * HID;
        float a = 0.f;
#pragma unroll 8
        for (int j = 0; j < 64; ++j) {
            int h = hc * 64 + j;
            a += dr[h] * Wd[(size_t)h * HID + k];
        }
        red[hc][kl] = a;
        __syncthreads();
        if (hc == 0) {
            float s = be[k] + bd[k];
#pragma unroll
            for (int c = 0; c < 8; ++c) s += red[c][kl];
            dproj[(size_t)b * HID + k] = s;
        }
    } else {
        int bz = blk - 640;
        out[bz * 256 + t] = 0.f;                // zero context region (16384 f32)
        if (bz == 0 && t < NB) sumacc[t] = 0.f;
    }
}

// ---------------------------------------------------------------------------
// K_main R14: 4 independent blocks/CU for phase-stagger.
// R13 post-mortem: 2->4 waves/SIMD gave only -11%; MfmaUtil 16.6 = MFMA
// floor/duration, i.e. time is lost in the SERIAL per-block phase bursts
// (stage->Kloop->epiA->epiB) that 2 co-resident blocks can't interleave
// (hbm duty 27%). Fix: BM=32, 256 threads, LDS ~36 KB -> 4 blocks/CU at the
// SAME 16-waves/CU register tier (<=128 total regs, m69): acc[2][8]=32 AGPR,
// fb as two 4-frag half-buffers (32 VGPR) with half-step prefetch (fbB loads
// issue under the fbA MFMA batch and vice versa). Components kept from
// R12/R13 (all measured-good): linear stream-once A staging, barrier-free
// K-loop, fragment-ordered B from L2, per-block K-chunk stagger.
// ---------------------------------------------------------------------------
__global__ __launch_bounds__(256, 4)
void k_main(const float* __restrict__ E, const short* __restrict__ Bp,
            const float* __restrict__ dproj, const float* __restrict__ Wv,
            float* __restrict__ out, float* __restrict__ sumacc) {
    __shared__ short As[BM][520];        // 32 x 520 shorts = 33.3 KB
    __shared__ float fbuf[512];
    __shared__ float pbuf[BM];

    const int tid  = threadIdx.x;
    const int wave = tid >> 6, lane = tid & 63;
    const int quad = lane >> 4, l15 = lane & 15;
    const int bid  = blockIdx.x;
    const int row0 = bid * BM;           // global row = b*4096 + s
    const int b    = bid >> 7;           // 128 blocks per batch
    const int stag = bid & 15;           // K-chunk stagger

    // ---- stage full A-tile, linear streaming: wave w -> rows 8w..8w+7 ----
    {
        const float4* src4 = (const float4*)(E + (size_t)(row0 + wave * 8) * HID);
#pragma unroll
        for (int i = 0; i < 16; ++i) {
            float4 v = src4[i * 64 + lane];          // 1 KB contiguous per instr
            int fo  = i * 256 + lane * 4;            // float offset in 8-row span
            int r8  = fo >> 9;                       // 0..7
            int col = fo & 511;
            union { unsigned u[2]; s16x4 s; } t;
            t.u[0] = cvtpk(v.x, v.y);
            t.u[1] = cvtpk(v.z, v.w);
            *(s16x4*)&As[wave * 8 + r8][col] = t.s;
        }
    }
    __syncthreads();                                  // the ONLY K-path barrier

    f32x4 acc[2][8];
#pragma unroll
    for (int r = 0; r < 2; ++r)
#pragma unroll
        for (int c = 0; c < 8; ++c) acc[r][c] = (f32x4){0.f, 0.f, 0.f, 0.f};

    // B fragment base: Bp[kc][nt = wave*8 + c][lane][8 shorts]
    const short* bpw = Bp + ((size_t)(wave * 8) * 64 + lane) * 8;

#define LOADB4(dst, kk, c0) do {                                         \
        const short* bsrc_ = bpw + (size_t)(kk) * 16384 + (c0) * 512;    \
        _Pragma("unroll")                                                \
        for (int c_ = 0; c_ < 4; ++c_)                                   \
            dst[c_] = *(const bf16x8*)(bsrc_ + c_ * 512);                \
    } while (0)

    bf16x8 fbA[4], fbB[4];
    LOADB4(fbA, stag, 0);
#pragma unroll
    for (int kc = 0; kc < 16; ++kc) {
        const int kcs = (stag + kc) & 15;
        // issue B-half loads for c=4..7 (fly under the fbA MFMA batch)
        LOADB4(fbB, kcs, 4);
        bf16x8 fa[2];
#pragma unroll
        for (int r = 0; r < 2; ++r)
            fa[r] = *(bf16x8*)&As[r * 16 + l15][kcs * 32 + quad * 8];
#pragma unroll
        for (int c = 0; c < 4; ++c)
#pragma unroll
            for (int r = 0; r < 2; ++r)
                acc[r][c] = __builtin_amdgcn_mfma_f32_16x16x32_bf16(fa[r], fbA[c], acc[r][c], 0, 0, 0);
        // issue A-half loads for next kc (fly under the fbB MFMA batch)
        if (kc < 15) LOADB4(fbA, (kcs + 1) & 15, 0);
#pragma unroll
        for (int c = 0; c < 4; ++c)
#pragma unroll
            for (int r = 0; r < 2; ++r)
                acc[r][c + 4] = __builtin_amdgcn_mfma_f32_16x16x32_bf16(fa[r], fbB[c], acc[r][c + 4], 0, 0, 0);
    }
#undef LOADB4

    // ---- epilogue a: score = sum_col tanh(acc + dproj[col]) * Wv[col] ----
    // acc[r][c][g] = enc_proj[row0 + r*16 + quad*4 + g][wave*128 + c*16 + l15]
    float part[2][4];
#pragma unroll
    for (int r = 0; r < 2; ++r)
#pragma unroll
        for (int g = 0; g < 4; ++g) part[r][g] = 0.f;
    const float* dp = dproj + (size_t)b * HID;
#pragma unroll
    for (int c = 0; c < 8; ++c) {
        int col = wave * 128 + c * 16 + l15;
        float dv = dp[col];
        float wv = Wv[col];
#pragma unroll
        for (int r = 0; r < 2; ++r)
#pragma unroll
            for (int g = 0; g < 4; ++g)
                part[r][g] += fast_tanh(acc[r][c][g] + dv) * wv;
    }
    // reduce across the 16 col-lanes (bits 0..3 of lane)
#pragma unroll
    for (int r = 0; r < 2; ++r)
#pragma unroll
        for (int g = 0; g < 4; ++g) {
            float v = part[r][g];
            v += __shfl_xor(v, 1); v += __shfl_xor(v, 2);
            v += __shfl_xor(v, 4); v += __shfl_xor(v, 8);
            part[r][g] = v;
        }
    if (l15 == 0) {
#pragma unroll
        for (int r = 0; r < 2; ++r)
#pragma unroll
            for (int g = 0; g < 4; ++g)
                fbuf[wave * 32 + r * 16 + quad * 4 + g] = part[r][g];
    }
    __syncthreads();
    if (tid < 32) {
        float s = fbuf[tid] + fbuf[32 + tid] + fbuf[64 + tid] + fbuf[96 + tid];
        float pv = __expf(s);           // unnormalized; b_v cancels in softmax
        pbuf[tid] = pv;
        out[(size_t)NB * HID + row0 + tid] = pv;   // weights region, normalized later
        float t2 = pv;
        t2 += __shfl_xor(t2, 1); t2 += __shfl_xor(t2, 2); t2 += __shfl_xor(t2, 4);
        t2 += __shfl_xor(t2, 8); t2 += __shfl_xor(t2, 16);
        if (tid == 0) atomicAdd(&sumacc[b], t2);
    }
    __syncthreads();

    // ---- epilogue b: partial context = sum_rows pv * E[row,:] (L1/L2-hot) ----
    const int hq = tid & 127, rh = tid >> 7;       // h = hq*4, rows rh*16..rh*16+15
    const float4* E4 = (const float4*)E;
    size_t cbase = (size_t)(row0 + rh * 16) * (HID / 4) + hq;
    float4 ca = {0.f, 0.f, 0.f, 0.f};
#pragma unroll 4
    for (int rr = 0; rr < 16; ++rr) {
        float w  = pbuf[rh * 16 + rr];
        float4 e = E4[cbase + (size_t)rr * (HID / 4)];
        ca.x += w * e.x; ca.y += w * e.y; ca.z += w * e.z; ca.w += w * e.w;
    }
    if (rh == 1) {
        fbuf[hq] = ca.x; fbuf[128 + hq] = ca.y; fbuf[256 + hq] = ca.z; fbuf[384 + hq] = ca.w;
    }
    __syncthreads();
    if (rh == 0) {
        ca.x += fbuf[hq]; ca.y += fbuf[128 + hq]; ca.z += fbuf[256 + hq]; ca.w += fbuf[384 + hq];
        float* cg = out + (size_t)b * HID + hq * 4;   // context region of d_out
        atomicAdd(cg + 0, ca.x); atomicAdd(cg + 1, ca.y);
        atomicAdd(cg + 2, ca.z); atomicAdd(cg + 3, ca.w);
    }
}

// ---------------------------------------------------------------------------
// K_finish: normalize in place, full-grid. 147456 floats / 256 = 576 blocks.
// ---------------------------------------------------------------------------
__global__ void k_finish(float* __restrict__ out, const float* __restrict__ sumacc) {
    int idx = blockIdx.x * 256 + threadIdx.x;
    if (idx < NB * HID) {
        out[idx] *= 1.0f / sumacc[idx >> 9];           // context: b = idx/HID
    } else {
        int w = idx - NB * HID;
        out[idx] *= 1.0f / sumacc[w >> 12];            // weights: b = w/SEQL
    }
}

extern "C" void kernel_launch(void* const* d_in, const int* in_sizes, int n_in,
                              void* d_out, int out_size, void* d_ws, size_t ws_size,
                              hipStream_t stream) {
    const float* E   = (const float*)d_in[0];
    const float* dec = (const float*)d_in[1];
    const float* We  = (const float*)d_in[2];
    const float* be  = (const float*)d_in[3];
    const float* Wd  = (const float*)d_in[4];
    const float* bd  = (const float*)d_in[5];
    const float* Wv  = (const float*)d_in[6];
    // d_in[7] = b_v: uniform shift per score -> cancels in softmax
    float* out = (float*)d_out;
    char*  ws  = (char*)d_ws;
    short* Bp     = (short*)(ws + WS_BP);
    float* dproj  = (float*)(ws + WS_DPROJ);
    float* sumacc = (float*)(ws + WS_SUM);

    k_pre<<<704, 256, 0, stream>>>(We, Bp, dec, Wd, be, bd, dproj, out, sumacc);
    k_main<<<NBLK, 256, 0, stream>>>(E, Bp, dproj, Wv, out, sumacc);
    k_finish<<<576, 256, 0, stream>>>(out, sumacc);
}

// Round 18
// 447.144 us; speedup vs baseline: 1.0820x; 1.0820x over previous
//
#include <hip/hip_runtime.h>
#include <hip/hip_bf16.h>

typedef __attribute__((ext_vector_type(8))) short bf16x8;
typedef __attribute__((ext_vector_type(4))) float f32x4;
typedef __attribute__((ext_vector_type(4))) short s16x4;

#define HID 512
#define NB 32
#define SEQL 4096
#define BM 64
#define NBLK 2048       // 131072 rows / 64

// workspace layout (bytes)
#define WS_BP    0              // packed bf16 W_enc: 512 KB
#define WS_DPROJ (512*1024)     // fp32 32x512: 64 KB
#define WS_SUM   (576*1024)     // fp32 32: 128 B

__device__ __forceinline__ short f2bf(float f) {
    unsigned u = __float_as_uint(f);
    unsigned r = (u + 0x7fffu + ((u >> 16) & 1u)) >> 16;   // RNE
    return (short)r;
}

__device__ __forceinline__ float fast_tanh(float x) {
    float e = __expf(2.0f * x);
    float r = __builtin_amdgcn_rcpf(e + 1.0f);
    return 1.0f - 2.0f * r;
}

// HW packed f32->bf16 RNE (no builtin on gfx950 — inline asm)
__device__ __forceinline__ unsigned cvtpk(float lo, float hi) {
    unsigned r;
    asm("v_cvt_pk_bf16_f32 %0, %1, %2" : "=v"(r) : "v"(lo), "v"(hi));
    return r;
}

// ---------------------------------------------------------------------------
// K_pre (unchanged, measured-good): (a) W_enc pack fp32->bf16 B-frag layout
// [blk 0..127], (b) dproj GEMV 8-way h-parallel [blk 128..639],
// (c) zero ctx + sumacc [blk 640..703]
// ---------------------------------------------------------------------------
__global__ void k_pre(const float* __restrict__ We, short* __restrict__ Bp,
                      const float* __restrict__ dec, const float* __restrict__ Wd,
                      const float* __restrict__ be, const float* __restrict__ bd,
                      float* __restrict__ dproj, float* __restrict__ out,
                      float* __restrict__ sumacc) {
    const int blk = blockIdx.x, t = threadIdx.x;
    if (blk < 128) {
        // Bp[kc32][nt][lane][j] = We[kc32*32 + (lane>>4)*8 + j][nt*16 + (lane&15)]
        int tid  = blk * 256 + t;
        int lane = tid & 63;
        int nt   = (tid >> 6) & 31;
        int kc   = tid >> 11;
        int k0   = kc * 32 + (lane >> 4) * 8;
        int n    = nt * 16 + (lane & 15);
        bf16x8 v;
#pragma unroll
        for (int j = 0; j < 8; ++j) v[j] = f2bf(We[(size_t)(k0 + j) * HID + n]);
        *(bf16x8*)&Bp[(size_t)tid * 8] = v;
    } else if (blk < 640) {
        __shared__ float red[8][33];
        int bid2 = blk - 128;
        int b  = bid2 >> 4, kg = bid2 & 15;     // 32 batches x 16 k-groups
        int kl = t & 31,    hc = t >> 5;        // 32 k-cols x 8 h-chunks
        int k  = kg * 32 + kl;
        const float* dr = dec + (size_t)b * HID;
        float a = 0.f;
#pragma unroll 8
        for (int j = 0; j < 64; ++j) {
            int h = hc * 64 + j;
            a += dr[h] * Wd[(size_t)h * HID + k];
        }
        red[hc][kl] = a;
        __syncthreads();
        if (hc == 0) {
            float s = be[k] + bd[k];
#pragma unroll
            for (int c = 0; c < 8; ++c) s += red[c][kl];
            dproj[(size_t)b * HID + k] = s;
        }
    } else {
        int bz = blk - 640;
        out[bz * 256 + t] = 0.f;                // zero context region (16384 f32)
        if (bz == 0 && t < NB) sumacc[t] = 0.f;
    }
}

// ---------------------------------------------------------------------------
// K_main R15: R13 (best measured: 171.5us) + 2-deep fb prefetch.
// R13's K-loop issued fb[nxt] loads right BEFORE the MFMAs, so each iter's
// MFMA batch waits on the MOST RECENT loads -> compiler's auto-waitcnt is
// effectively vmcnt(0): full queue drain + exposed L2 latency 16x/block.
// R15: prologue loads fb for kc AND kc+1; each iter consumes fb[cur] and
// refills it for kc+2 AFTER the MFMAs. The MFMAs of iter kc+1 then need the
// OLDER 4 of 8 outstanding loads -> vmcnt(4): 4 loads stay in flight
// permanently (T4 at register level). Zero extra registers, full unroll
// keeps fb indices static (rule #20). Everything else verbatim R13.
// R14 lesson encoded: BM stays 64 (BM=32 doubles B L2 traffic, -29% measured).
// ---------------------------------------------------------------------------
__global__ __launch_bounds__(512, 4)
void k_main(const float* __restrict__ E, const short* __restrict__ Bp,
            const float* __restrict__ dproj, const float* __restrict__ Wv,
            float* __restrict__ out, float* __restrict__ sumacc) {
    __shared__ short As[BM][520];        // 64 x 520 shorts = 66.6 KB (1040 B rows)
    __shared__ float fbuf[1024];
    __shared__ float pbuf[BM];

    const int tid  = threadIdx.x;
    const int wave = tid >> 6, lane = tid & 63;
    const int quad = lane >> 4, l15 = lane & 15;
    const int bid  = blockIdx.x;
    const int row0 = bid * BM;           // global row = b*4096 + s
    const int b    = bid >> 6;           // 64 blocks per batch
    const int stag = bid & 15;           // K-chunk stagger

    // ---- stage full A-tile, linear streaming: wave w -> rows 8w..8w+7 ----
    {
        const float4* src4 = (const float4*)(E + (size_t)(row0 + wave * 8) * HID);
#pragma unroll
        for (int i = 0; i < 16; ++i) {
            float4 v = src4[i * 64 + lane];          // 1 KB contiguous per instr
            int fo  = i * 256 + lane * 4;            // float offset in 8-row span
            int r8  = fo >> 9;                       // 0..7
            int col = fo & 511;
            union { unsigned u[2]; s16x4 s; } t;
            t.u[0] = cvtpk(v.x, v.y);
            t.u[1] = cvtpk(v.z, v.w);
            *(s16x4*)&As[wave * 8 + r8][col] = t.s;
        }
    }
    __syncthreads();                                  // the ONLY K-path barrier

    f32x4 acc[4][4];
#pragma unroll
    for (int r = 0; r < 4; ++r)
#pragma unroll
        for (int c = 0; c < 4; ++c) acc[r][c] = (f32x4){0.f, 0.f, 0.f, 0.f};

    // B fragment base: Bp[kc][nt = wave*4 + c][lane][8 shorts]
    const short* bpw = Bp + ((size_t)(wave * 4) * 64 + lane) * 8;

#define LOADB(dst, kk) do {                                            \
        const short* bsrc_ = bpw + (size_t)(kk) * 16384;               \
        _Pragma("unroll")                                              \
        for (int c_ = 0; c_ < 4; ++c_)                                 \
            dst[c_] = *(const bf16x8*)(bsrc_ + c_ * 512);              \
    } while (0)

    bf16x8 fb[2][4];
    LOADB(fb[0], stag);                              // kc = 0
    LOADB(fb[1], (stag + 1) & 15);                   // kc = 1
#pragma unroll
    for (int kc = 0; kc < 16; ++kc) {
        const int cur = kc & 1;                      // compile-time after unroll
        const int kcs = (stag + kc) & 15;
        bf16x8 fa[4];
#pragma unroll
        for (int r = 0; r < 4; ++r)
            fa[r] = *(bf16x8*)&As[r * 16 + l15][kcs * 32 + quad * 8];
#pragma unroll
        for (int c = 0; c < 4; ++c)
#pragma unroll
            for (int r = 0; r < 4; ++r)
                acc[r][c] = __builtin_amdgcn_mfma_f32_16x16x32_bf16(fa[r], fb[cur][c], acc[r][c], 0, 0, 0);
        // refill the just-consumed buffer for kc+2 (issue-after-consume:
        // next iter's MFMAs wait on OLDER loads -> counted vmcnt, no drain)
        if (kc < 14) LOADB(fb[cur], (kcs + 2) & 15);
    }
#undef LOADB

    // ---- epilogue a: score = sum_col tanh(acc + dproj[col]) * Wv[col] ----
    // acc[r][c][g] = enc_proj[row0 + r*16 + quad*4 + g][wave*64 + c*16 + l15]
    float part[4][4];
#pragma unroll
    for (int r = 0; r < 4; ++r)
#pragma unroll
        for (int g = 0; g < 4; ++g) part[r][g] = 0.f;
    const float* dp = dproj + (size_t)b * HID;
#pragma unroll
    for (int c = 0; c < 4; ++c) {
        int col = wave * 64 + c * 16 + l15;
        float dv = dp[col];
        float wv = Wv[col];
#pragma unroll
        for (int r = 0; r < 4; ++r)
#pragma unroll
            for (int g = 0; g < 4; ++g)
                part[r][g] += fast_tanh(acc[r][c][g] + dv) * wv;
    }
    // reduce across the 16 col-lanes (bits 0..3 of lane)
#pragma unroll
    for (int r = 0; r < 4; ++r)
#pragma unroll
        for (int g = 0; g < 4; ++g) {
            float v = part[r][g];
            v += __shfl_xor(v, 1); v += __shfl_xor(v, 2);
            v += __shfl_xor(v, 4); v += __shfl_xor(v, 8);
            part[r][g] = v;
        }
    if (l15 == 0) {
#pragma unroll
        for (int r = 0; r < 4; ++r)
#pragma unroll
            for (int g = 0; g < 4; ++g)
                fbuf[wave * 64 + r * 16 + quad * 4 + g] = part[r][g];
    }
    __syncthreads();
    if (tid < 64) {
        float s = fbuf[tid];
#pragma unroll
        for (int w = 1; w < 8; ++w) s += fbuf[w * 64 + tid];
        float pv = __expf(s);           // unnormalized; b_v cancels in softmax
        pbuf[tid] = pv;
        out[(size_t)NB * HID + row0 + tid] = pv;   // weights region, normalized later
        float t2 = pv;
        t2 += __shfl_xor(t2, 1);  t2 += __shfl_xor(t2, 2);  t2 += __shfl_xor(t2, 4);
        t2 += __shfl_xor(t2, 8);  t2 += __shfl_xor(t2, 16); t2 += __shfl_xor(t2, 32);
        if (tid == 0) atomicAdd(&sumacc[b], t2);
    }
    __syncthreads();

    // ---- epilogue b: partial context = sum_rows pv * E[row,:] (L2-hot) ----
    const int hq = tid & 127, rh = tid >> 7;       // h = hq*4, rows rh*16..rh*16+15
    const float4* E4 = (const float4*)E;
    size_t cbase = (size_t)(row0 + rh * 16) * (HID / 4) + hq;
    float4 ca = {0.f, 0.f, 0.f, 0.f};
#pragma unroll 4
    for (int rr = 0; rr < 16; ++rr) {
        float w  = pbuf[rh * 16 + rr];
        float4 e = E4[cbase + (size_t)rr * (HID / 4)];
        ca.x += w * e.x; ca.y += w * e.y; ca.z += w * e.z; ca.w += w * e.w;
    }
    // 4-group reduction tree in fbuf (1024 floats)
    if (rh >= 2) {
        int base = (rh - 2) * 512;
        fbuf[base + hq] = ca.x;        fbuf[base + 128 + hq] = ca.y;
        fbuf[base + 256 + hq] = ca.z;  fbuf[base + 384 + hq] = ca.w;
    }
    __syncthreads();
    if (rh < 2) {
        int base = rh * 512;
        ca.x += fbuf[base + hq];       ca.y += fbuf[base + 128 + hq];
        ca.z += fbuf[base + 256 + hq]; ca.w += fbuf[base + 384 + hq];
        if (rh == 1) {   // write into region 512 (own source, already consumed)
            fbuf[512 + hq] = ca.x;        fbuf[512 + 128 + hq] = ca.y;
            fbuf[512 + 256 + hq] = ca.z;  fbuf[512 + 384 + hq] = ca.w;
        }
    }
    __syncthreads();
    if (rh == 0) {
        ca.x += fbuf[512 + hq];       ca.y += fbuf[512 + 128 + hq];
        ca.z += fbuf[512 + 256 + hq]; ca.w += fbuf[512 + 384 + hq];
        float* cg = out + (size_t)b * HID + hq * 4;   // context region of d_out
        atomicAdd(cg + 0, ca.x); atomicAdd(cg + 1, ca.y);
        atomicAdd(cg + 2, ca.z); atomicAdd(cg + 3, ca.w);
    }
}

// ---------------------------------------------------------------------------
// K_finish: normalize in place, full-grid. 147456 floats / 256 = 576 blocks.
// ---------------------------------------------------------------------------
__global__ void k_finish(float* __restrict__ out, const float* __restrict__ sumacc) {
    int idx = blockIdx.x * 256 + threadIdx.x;
    if (idx < NB * HID) {
        out[idx] *= 1.0f / sumacc[idx >> 9];           // context: b = idx/HID
    } else {
        int w = idx - NB * HID;
        out[idx] *= 1.0f / sumacc[w >> 12];            // weights: b = w/SEQL
    }
}

extern "C" void kernel_launch(void* const* d_in, const int* in_sizes, int n_in,
                              void* d_out, int out_size, void* d_ws, size_t ws_size,
                              hipStream_t stream) {
    const float* E   = (const float*)d_in[0];
    const float* dec = (const float*)d_in[1];
    const float* We  = (const float*)d_in[2];
    const float* be  = (const float*)d_in[3];
    const float* Wd  = (const float*)d_in[4];
    const float* bd  = (const float*)d_in[5];
    const float* Wv  = (const float*)d_in[6];
    // d_in[7] = b_v: uniform shift per score -> cancels in softmax
    float* out = (float*)d_out;
    char*  ws  = (char*)d_ws;
    short* Bp     = (short*)(ws + WS_BP);
    float* dproj  = (float*)(ws + WS_DPROJ);
    float* sumacc = (float*)(ws + WS_SUM);

    k_pre<<<704, 256, 0, stream>>>(We, Bp, dec, Wd, be, bd, dproj, out, sumacc);
    k_main<<<NBLK, 512, 0, stream>>>(E, Bp, dproj, Wv, out, sumacc);
    k_finish<<<576, 256, 0, stream>>>(out, sumacc);
}